// Round 8
// baseline (405.401 us; speedup 1.0000x reference)
//
#include <hip/hip_runtime.h>
#include <hip/hip_bf16.h>

typedef __hip_bfloat16 bf16;
typedef short bf16x8 __attribute__((ext_vector_type(8)));
typedef float f32x4 __attribute__((ext_vector_type(4)));

#define CC 16
#define PP 256
#define DMH 512
#define DIH 1024
#define MM (CC*PP)   /* 4096 rows (c,p) */
#define NST 16
#define NDT 32

__device__ __forceinline__ float b2f(bf16 v){ return __bfloat162float(v); }
__device__ __forceinline__ bf16  f2b(float v){ return __float2bfloat16(v); }

__device__ __forceinline__ float geluf(float x){
  float x3 = x*x*x;
  return 0.5f*x*(1.0f + tanhf(0.7978845608028654f*x + 0.035677408136300125f*x3));
}
__device__ __forceinline__ float softplusf(float x){
  if (x > 20.0f) return x;
  return log1pf(expf(x));
}

__device__ __forceinline__ void g2l16(const bf16* g, bf16* l){
  __builtin_amdgcn_global_load_lds(
      (const __attribute__((address_space(1))) void*)g,
      (__attribute__((address_space(3))) void*)(uint32_t)(uintptr_t)l,
      16, 0, 0);
}

__global__ void f32_to_bf16(const float* __restrict__ src, bf16* __restrict__ dst, int n4){
  int i = blockIdx.x*256 + threadIdx.x;
  if (i >= n4) return;
  float4 v = ((const float4*)src)[i];
  bf16 o[4] = {f2b(v.x), f2b(v.y), f2b(v.z), f2b(v.w)};
  *(ushort4*)&dst[(size_t)i*4] = *(const ushort4*)o;
}

__global__ void zerof4(float4* __restrict__ p, int n4){
  int i = blockIdx.x*256 + threadIdx.x;
  if (i < n4) p[i] = make_float4(0.f,0.f,0.f,0.f);
}

// conv_w (fp32) [o][i][tap] -> cwT bf16 [tap][o][i]
__global__ void repack_cw(const float* __restrict__ cw, bf16* __restrict__ cwT){
  const size_t idx = (size_t)blockIdx.x*256 + threadIdx.x;   // o*1024 + i
  const float4 v = *(const float4*)(cw + idx*4);
  cwT[idx]                     = f2b(v.x);
  cwT[(size_t)DIH*DIH   + idx] = f2b(v.y);
  cwT[(size_t)2*DIH*DIH + idx] = f2b(v.z);
  cwT[(size_t)3*DIH*DIH + idx] = f2b(v.w);
}

// in_w xi-half [i<1024][m<512] -> inwT bf16 [m][i]
__global__ void tr_inw(const float* __restrict__ in_w, bf16* __restrict__ out){
  int t = blockIdx.x*256 + threadIdx.x;   // 512K
  int m = t >> 10, i = t & 1023;
  out[t] = f2b(in_w[(size_t)i*DMH + m]);
}

// cb2[o] = conv_b[o] + sum_i (sum_k conv_w[o,i,k]) * in_b[i]
__global__ void fold_bias(const float* __restrict__ cw, const float* __restrict__ in_b,
                          const float* __restrict__ conv_b, float* __restrict__ cb2){
  const int o = blockIdx.x;
  const int tid = threadIdx.x;
  float acc = 0.0f;
  #pragma unroll
  for (int t = 0; t < 4; t++){
    int i = tid + t*256;
    const float4 w = *(const float4*)(cw + (size_t)o*4096 + (size_t)i*4);
    acc += (w.x + w.y + w.z + w.w) * in_b[i];
  }
  for (int off = 32; off; off >>= 1) acc += __shfl_down(acc, off);
  __shared__ float ls[4];
  if ((tid & 63) == 0) ls[tid >> 6] = acc;
  __syncthreads();
  if (tid == 0) cb2[o] = conv_b[o] + ls[0] + ls[1] + ls[2] + ls[3];
}

// ---------------- MFMA GEMM: C[m,n] = epi( sum_k A[m,k]*B[n,k] + bias[n] ) -------------
// 128 x (32*NFRAG) tile, BK=64, 4 waves. CONV=1: A rows edge-clamped shifted (tap=k0>>9).
// blockIdx.z: azs = A element offset per z, ozs = out n-offset per z, kzs = k offset per z.
// EPI: 0 fp32+bias | 1 bf16 gelu | 2 bf16 gelu(gelu) | 3 raw bf16 no-bias (fold)
//      4 fp32 atomicAdd (+bias only on z==0)  [split-K]
#define TBK 64

template<int EPI, int CONV, int NFRAG>
__launch_bounds__(256)
__global__ void mfma_gemm(const bf16* __restrict__ A, int lda,
                          const bf16* __restrict__ B, int ldb,
                          const float* __restrict__ bias,
                          float* __restrict__ outF,
                          bf16* __restrict__ outB0,
                          int ldo, int K, int azs, int ozs, int kzs)
{
  __shared__ bf16 As[128*TBK];           // 16 KB
  __shared__ bf16 Bs[32*NFRAG*TBK];      // 4/8 KB
  const int tid  = threadIdx.x;
  const int lane = tid & 63;
  const int wave = tid >> 6;
  const int wr = (wave >> 1) * 64;
  const int wc = (wave & 1) * 16 * NFRAG;
  const int mBase = blockIdx.x * 128;
  const int nBase = blockIdx.y * (32*NFRAG);
  A += (size_t)blockIdx.z * azs;
  const int nOff = blockIdx.z * ozs;
  const int koff = blockIdx.z * kzs;

  f32x4 acc[4][NFRAG] = {};

  for (int k0 = 0; k0 < K; k0 += TBK) {
    __syncthreads();
    #pragma unroll
    for (int it = 0; it < 4; it++) {      // As: 1024 chunks of 16B
      const int idx = it*256 + tid;
      const int r = idx >> 3, c16 = idx & 7;
      const bf16* ga;
      if (CONV) {
        const int tap = k0 >> 9, kk = k0 & 511;
        const int m = mBase + r;
        const int cc = m >> 8;
        int p = (m & 255) + tap - 2;
        p = min(max(p, 0), PP-1);
        ga = A + ((size_t)(cc*PP + p))*DMH + kk + c16*8;
      } else {
        ga = A + (size_t)(mBase + r)*lda + koff + k0 + c16*8;
      }
      g2l16(ga, &As[(size_t)idx*8]);
    }
    #pragma unroll
    for (int it = 0; it < NFRAG; it++) {  // Bs: 256*NFRAG chunks of 16B
      const int idx = it*256 + tid;
      const int r = idx >> 3, c16 = idx & 7;
      const bf16* gb = B + (size_t)(nBase + r)*ldb + koff + k0 + c16*8;
      g2l16(gb, &Bs[(size_t)idx*8]);
    }
    __syncthreads();
    #pragma unroll
    for (int ks = 0; ks < 2; ks++) {
      bf16x8 af[4], bfr[NFRAG];
      #pragma unroll
      for (int r = 0; r < 4; r++)
        af[r] = *(const bf16x8*)&As[(wr + r*16 + (lane & 15))*TBK + ks*32 + (lane>>4)*8];
      #pragma unroll
      for (int c = 0; c < NFRAG; c++)
        bfr[c] = *(const bf16x8*)&Bs[(wc + c*16 + (lane & 15))*TBK + ks*32 + (lane>>4)*8];
      #pragma unroll
      for (int r = 0; r < 4; r++)
        #pragma unroll
        for (int c = 0; c < NFRAG; c++)
          acc[r][c] = __builtin_amdgcn_mfma_f32_16x16x32_bf16(af[r], bfr[c], acc[r][c], 0, 0, 0);
    }
  }

  const int col0 = lane & 15;
  const int row0 = (lane >> 4) * 4;
  #pragma unroll
  for (int r = 0; r < 4; r++) {
    #pragma unroll
    for (int c = 0; c < NFRAG; c++) {
      #pragma unroll
      for (int reg = 0; reg < 4; reg++) {
        const int m = mBase + wr + r*16 + row0 + reg;
        const int n = nBase + wc + c*16 + col0;
        const float av = acc[r][c][reg];
        if (EPI == 0) {
          outF[(size_t)m*ldo + n] = av + bias[n];
        } else if (EPI == 1) {
          outB0[(size_t)m*ldo + n] = f2b(geluf(av + bias[n]));
        } else if (EPI == 2) {
          outB0[(size_t)m*ldo + n] = f2b(geluf(geluf(av + bias[n])));
        } else if (EPI == 3) {
          outB0[(size_t)m*ldo + n + nOff] = f2b(av);
        } else {
          const float vv = av + ((blockIdx.z == 0) ? bias[n] : 0.0f);
          atomicAdd(&outF[(size_t)m*ldo + n], vv);
        }
      }
    }
  }
}

// ---------------- dt GEMM (K=32) + pack {dt fp32 | xi bf16 | gz bf16} -> pk ----------
__launch_bounds__(256)
__global__ void dt_pack(const float* __restrict__ xdb,   // [M,64], cols 0..31 = dt_raw
                        const float* __restrict__ dt_w,  // [DIH,32]
                        const float* __restrict__ dt_b,  // [DIH]
                        const bf16* __restrict__ xi,     // [M,DIH]
                        const bf16* __restrict__ gz,     // [M,DIH]
                        uint2* __restrict__ pk)          // [M,DIH]
{
  __shared__ float As[64][36];   // +4 pad: rows spread across banks
  __shared__ float Bw[64][36];
  const int tid = threadIdx.x;
  const int m0 = blockIdx.x * 64;
  const int d0 = blockIdx.y * 64;
  {
    #pragma unroll
    for (int t = 0; t < 2; t++){
      int q = tid*2 + t;            // 512 float4 per matrix
      int r = q >> 3, c4 = (q & 7)*4;
      *(float4*)&As[r][c4] = *(const float4*)&xdb[(size_t)(m0+r)*64 + c4];
      *(float4*)&Bw[r][c4] = *(const float4*)&dt_w[(size_t)(d0+r)*NDT + c4];
    }
  }
  __syncthreads();
  const int tx = tid & 15, ty = tid >> 4;
  float acc[4][4];
  #pragma unroll
  for (int i = 0; i < 4; i++)
    #pragma unroll
    for (int j = 0; j < 4; j++) acc[i][j] = dt_b[d0 + tx*4 + j];
  #pragma unroll
  for (int k = 0; k < 32; k += 4){
    float4 a4[4], b4[4];
    #pragma unroll
    for (int i = 0; i < 4; i++) a4[i] = *(const float4*)&As[ty*4+i][k];
    #pragma unroll
    for (int j = 0; j < 4; j++) b4[j] = *(const float4*)&Bw[tx*4+j][k];
    #pragma unroll
    for (int i = 0; i < 4; i++)
      #pragma unroll
      for (int j = 0; j < 4; j++)
        acc[i][j] += a4[i].x*b4[j].x + a4[i].y*b4[j].y + a4[i].z*b4[j].z + a4[i].w*b4[j].w;
  }
  #pragma unroll
  for (int i = 0; i < 4; i++){
    const int m = m0 + ty*4 + i;
    const int d = d0 + tx*4;
    const ushort4 xh = *(const ushort4*)((const ushort*)xi + (size_t)m*DIH + d);
    const ushort4 gh = *(const ushort4*)((const ushort*)gz + (size_t)m*DIH + d);
    const ushort xs[4] = {xh.x, xh.y, xh.z, xh.w};
    const ushort gs[4] = {gh.x, gh.y, gh.z, gh.w};
    uint2 o[4];
    #pragma unroll
    for (int j = 0; j < 4; j++){
      o[j].x = __float_as_uint(softplusf(acc[i][j]));
      o[j].y = (uint)xs[j] | ((uint)gs[j] << 16);
    }
    *(uint4*)&pk[(size_t)m*DIH + d]     = *(uint4*)&o[0];
    *(uint4*)&pk[(size_t)m*DIH + d + 2] = *(uint4*)&o[2];
  }
}

// ---------------- chunked selective scan ----------------
// Linear recurrence s_p = e_p*s_{p-1} + u_p  =>  s_p(s_in) = s_p(0) + (prod e)*s_in.
// Phase A: per (c,d,n,chunk of 16): run from s=0, emit (prod_e, s_partial).
// Phase B: per (c,d,n): 16-step serial scan over chunk summaries -> s_in[g].
// Phase C: replay each chunk from s_in, emit y (and final state at g=15).
__launch_bounds__(256)
__global__ void scan_a(const uint2* __restrict__ pk, const float* __restrict__ xdb,
                       const float* __restrict__ A_log, float2* __restrict__ AS)
{
  const int b = blockIdx.x;              // c*1024 + d
  const int c = b >> 10, d = b & 1023;
  const int tid = threadIdx.x;
  const int n = tid & 15, g = tid >> 4;  // tid == g*16+n
  const int m0 = c*PP + g*16;
  const float a = -__expf(A_log[(size_t)d*NST + n]);
  const uint2* qp = pk + (size_t)m0*DIH + d;
  const float* bp = xdb + (size_t)m0*64 + 32 + n;
  uint2 q[16]; float Bv[16];
  #pragma unroll
  for (int j = 0; j < 16; j++){ q[j] = qp[(size_t)j*DIH]; Bv[j] = bp[j*64]; }
  float s = 0.f, Ap = 1.f;
  #pragma unroll
  for (int j = 0; j < 16; j++){
    const float dtv = __uint_as_float(q[j].x);
    bf16 xh; *(ushort*)&xh = (ushort)(q[j].y & 0xffffu);
    const float e = __expf(dtv*a);
    s = s*e + (dtv*b2f(xh))*Bv[j];
    Ap *= e;
  }
  float2 o; o.x = Ap; o.y = s;
  AS[(size_t)b*256 + tid] = o;
}

__launch_bounds__(256)
__global__ void scan_b(const float2* __restrict__ AS, const float* __restrict__ s0,
                       float* __restrict__ sIn)
{
  const int b = blockIdx.x;              // c*64 + dg (1024 blocks)
  const int c = b >> 6, dg = b & 63;
  const int tid = threadIdx.x;
  const int d = dg*16 + (tid >> 4), n = tid & 15;
  float s = s0[((size_t)c*DIH + d)*NST + n];
  const size_t base = ((size_t)(c*DIH + d))*256 + n;
  #pragma unroll
  for (int g = 0; g < 16; g++){
    sIn[base + g*16] = s;
    const float2 f = AS[base + g*16];
    s = f.y + f.x*s;
  }
}

__launch_bounds__(256)
__global__ void scan_c(const uint2* __restrict__ pk, const float* __restrict__ xdb,
                       const float* __restrict__ A_log, const float* __restrict__ Dp,
                       const float* __restrict__ sIn,
                       bf16* __restrict__ ypre, float* __restrict__ state_out)
{
  const int b = blockIdx.x;              // c*1024 + d
  const int c = b >> 10, d = b & 1023;
  const int tid = threadIdx.x;
  const int n = tid & 15, g = tid >> 4;
  const int m0 = c*PP + g*16;
  const float a = -__expf(A_log[(size_t)d*NST + n]);
  const float Dv = Dp[d];
  const uint2* qp = pk + (size_t)m0*DIH + d;
  const float* bp = xdb + (size_t)m0*64 + 32 + n;
  const float* cp = bp + NST;
  uint2 q[16]; float Bv[16], Cv[16];
  #pragma unroll
  for (int j = 0; j < 16; j++){
    q[j] = qp[(size_t)j*DIH]; Bv[j] = bp[j*64]; Cv[j] = cp[j*64];
  }
  float s = sIn[(size_t)b*256 + tid];
  bf16* yp = ypre + (size_t)m0*DIH + d;
  #pragma unroll
  for (int j = 0; j < 16; j++){
    const float dtv = __uint_as_float(q[j].x);
    bf16 xh; *(ushort*)&xh = (ushort)(q[j].y & 0xffffu);
    bf16 gh; *(ushort*)&gh = (ushort)(q[j].y >> 16);
    const float xiv = b2f(xh);
    const float e = __expf(dtv*a);
    s = s*e + (dtv*xiv)*Bv[j];
    float y = s*Cv[j];
    y += __shfl_xor(y, 1);
    y += __shfl_xor(y, 2);
    y += __shfl_xor(y, 4);
    y += __shfl_xor(y, 8);
    if (n == 0) yp[(size_t)j*DIH] = f2b((y + Dv*xiv) * b2f(gh));
  }
  if (g == 15) state_out[((size_t)c*DIH + d)*NST + n] = s;
}

extern "C" void kernel_launch(void* const* d_in, const int* in_sizes, int n_in,
                              void* d_out, int out_size, void* d_ws, size_t ws_size,
                              hipStream_t stream) {
  const float* x       = (const float*)d_in[0];
  const float* s0      = (const float*)d_in[1];
  const float* in_w    = (const float*)d_in[2];
  const float* in_b    = (const float*)d_in[3];
  const float* conv_w  = (const float*)d_in[4];
  const float* conv_b  = (const float*)d_in[5];
  const float* param_w = (const float*)d_in[6];
  const float* param_b = (const float*)d_in[7];
  const float* dt_w    = (const float*)d_in[8];
  const float* dt_b    = (const float*)d_in[9];
  const float* out_w   = (const float*)d_in[10];
  const float* out_b   = (const float*)d_in[11];
  const float* A_log   = (const float*)d_in[12];
  const float* Dp      = (const float*)d_in[13];

  char* ws = (char*)d_ws;
  uint2*  pk    = (uint2*)ws;  ws += (size_t)MM*DIH*8;     // 32 MB
  float*  xdb   = (float*)ws;  ws += (size_t)MM*64*4;      //  1 MB
  float*  cb2   = (float*)ws;  ws += 4096;                 //  4 KB
  bf16*   ypre  = (bf16*)ws;   ws += (size_t)MM*DIH*2;     //  8 MB
  bf16*   outwb = (bf16*)ws;   ws += (size_t)DMH*DIH*2;    //  1 MB
  bf16*   pwb   = (bf16*)ws;   ws += (size_t)64*DIH*2;     // 128 KB
  char*   U     = ws;          ws += (size_t)48*1024*1024; // union region, 48 MB
  // early-phase tenants of U (all dead before scan_a):
  bf16* xi   = (bf16*)(U);
  bf16* gz   = (bf16*)(U + (size_t) 8*1024*1024);
  bf16* Wfb  = (bf16*)(U + (size_t)16*1024*1024);
  bf16* xbf  = (bf16*)(U + (size_t)20*1024*1024);
  bf16* inwz = (bf16*)(U + (size_t)24*1024*1024);
  bf16* inwT = (bf16*)(U + (size_t)25*1024*1024);
  bf16* cwT  = (bf16*)(U + (size_t)26*1024*1024);
  // scan-phase tenants of U:
  float2* AS  = (float2*)(U);                              // 32 MB
  float*  sIn = (float*)(U + (size_t)32*1024*1024);        // 16 MB

  float* y_out  = (float*)d_out;                           // [C,P,DM] fp32
  float* st_out = y_out + (size_t)MM*DMH;                  // [C,DI,16] fp32

  // casts / repacks / fold prep
  f32_to_bf16<<<MM*DMH/4/256, 256, 0, stream>>>(x, xbf, MM*DMH/4);
  f32_to_bf16<<<DIH*DMH/4/256, 256, 0, stream>>>(in_w + (size_t)DIH*DMH, inwz, DIH*DMH/4);
  f32_to_bf16<<<DMH*DIH/4/256, 256, 0, stream>>>(out_w, outwb, DMH*DIH/4);
  f32_to_bf16<<<64*DIH/4/256, 256, 0, stream>>>(param_w, pwb, 64*DIH/4);
  repack_cw<<<DIH*DIH/256, 256, 0, stream>>>(conv_w, cwT);
  tr_inw<<<DMH*DIH/256, 256, 0, stream>>>(in_w, inwT);
  fold_bias<<<DIH, 256, 0, stream>>>(conv_w, in_b, conv_b, cb2);
  zerof4<<<MM*64/4/256, 256, 0, stream>>>((float4*)xdb, MM*64/4);

  // fold: Wf[k][o][m] = sum_i conv_w[o,i,k]*in_w[i,m]   (4 taps via grid.z)
  mfma_gemm<3,0,2><<<dim3(DIH/128, DMH/64, 4), 256, 0, stream>>>(
      cwT, DIH, inwT, DIH, nullptr, nullptr, Wfb, 4*DMH, DIH, DIH*DIH, DMH, 0);
  // z-half in_proj: gelu(gelu(x @ in_w_z^T + b_z)) -> gz (contiguous bf16)
  mfma_gemm<2,0,2><<<dim3(MM/128, DIH/64), 256, 0, stream>>>(
      xbf, DMH, inwz, DMH, in_b + DIH, nullptr, gz, DIH, DMH, 0, 0, 0);
  // fused conv: gelu( sum_tap x[clamp] @ Wf_tap^T + cb2 ) -> xi (contiguous bf16)
  mfma_gemm<1,1,2><<<dim3(MM/128, DIH/64), 256, 0, stream>>>(
      xbf, DMH, Wfb, 4*DMH, cb2, nullptr, xi, DIH, 4*DMH, 0, 0, 0);
  // x_db = xi @ param_w.T + param_b   (MFMA split-K=8, fp32 atomics into zeroed xdb)
  mfma_gemm<4,0,2><<<dim3(MM/128, 1, 8), 256, 0, stream>>>(
      xi, DIH, pwb, DIH, param_b, xdb, nullptr, 64, 128, 0, 0, 128);
  // dt = softplus(x_db[:,:32] @ dt_w.T + dt_b), pack {dt|xi|gz} -> pk (coalesced)
  dt_pack<<<dim3(MM/64, DIH/64), 256, 0, stream>>>(xdb, dt_w, dt_b, xi, gz, pk);
  // chunked scan
  scan_a<<<CC*DIH, 256, 0, stream>>>(pk, xdb, A_log, AS);
  scan_b<<<CC*64, 256, 0, stream>>>(AS, s0, sIn);
  scan_c<<<CC*DIH, 256, 0, stream>>>(pk, xdb, A_log, Dp, sIn, ypre, st_out);
  // out projection
  mfma_gemm<0,0,1><<<dim3(MM/128, DMH/32), 256, 0, stream>>>(
      ypre, DIH, outwb, DIH, out_b, y_out, nullptr, DMH, DIH, 0, 0, 0);
}

// Round 9
// 373.653 us; speedup vs baseline: 1.0850x; 1.0850x over previous
//
#include <hip/hip_runtime.h>
#include <hip/hip_bf16.h>

typedef __hip_bfloat16 bf16;
typedef short bf16x8 __attribute__((ext_vector_type(8)));
typedef float f32x4 __attribute__((ext_vector_type(4)));

#define CC 16
#define PP 256
#define DMH 512
#define DIH 1024
#define MM (CC*PP)   /* 4096 rows (c,p) */
#define NST 16
#define NDT 32

__device__ __forceinline__ float b2f(bf16 v){ return __bfloat162float(v); }
__device__ __forceinline__ bf16  f2b(float v){ return __float2bfloat16(v); }

__device__ __forceinline__ float geluf(float x){
  float x3 = x*x*x;
  return 0.5f*x*(1.0f + tanhf(0.7978845608028654f*x + 0.035677408136300125f*x3));
}
__device__ __forceinline__ float softplusf(float x){
  if (x > 20.0f) return x;
  return log1pf(expf(x));
}

__device__ __forceinline__ void g2l16(const bf16* g, bf16* l){
  __builtin_amdgcn_global_load_lds(
      (const __attribute__((address_space(1))) void*)g,
      (__attribute__((address_space(3))) void*)(uint32_t)(uintptr_t)l,
      16, 0, 0);
}

__global__ void f32_to_bf16(const float* __restrict__ src, bf16* __restrict__ dst, int n4){
  int i = blockIdx.x*256 + threadIdx.x;
  if (i >= n4) return;
  float4 v = ((const float4*)src)[i];
  bf16 o[4] = {f2b(v.x), f2b(v.y), f2b(v.z), f2b(v.w)};
  *(ushort4*)&dst[(size_t)i*4] = *(const ushort4*)o;
}

__global__ void zerof4(float4* __restrict__ p, int n4){
  int i = blockIdx.x*256 + threadIdx.x;
  if (i < n4) p[i] = make_float4(0.f,0.f,0.f,0.f);
}

// conv_w (fp32) [o][i][tap] -> cwT bf16 [tap][o][i]
__global__ void repack_cw(const float* __restrict__ cw, bf16* __restrict__ cwT){
  const size_t idx = (size_t)blockIdx.x*256 + threadIdx.x;   // o*1024 + i
  const float4 v = *(const float4*)(cw + idx*4);
  cwT[idx]                     = f2b(v.x);
  cwT[(size_t)DIH*DIH   + idx] = f2b(v.y);
  cwT[(size_t)2*DIH*DIH + idx] = f2b(v.z);
  cwT[(size_t)3*DIH*DIH + idx] = f2b(v.w);
}

// in_w xi-half [i<1024][m<512] -> inwT bf16 [m][i]
__global__ void tr_inw(const float* __restrict__ in_w, bf16* __restrict__ out){
  int t = blockIdx.x*256 + threadIdx.x;   // 512K
  int m = t >> 10, i = t & 1023;
  out[t] = f2b(in_w[(size_t)i*DMH + m]);
}

// cb2[o] = conv_b[o] + sum_i (sum_k conv_w[o,i,k]) * in_b[i]
__global__ void fold_bias(const float* __restrict__ cw, const float* __restrict__ in_b,
                          const float* __restrict__ conv_b, float* __restrict__ cb2){
  const int o = blockIdx.x;
  const int tid = threadIdx.x;
  float acc = 0.0f;
  #pragma unroll
  for (int t = 0; t < 4; t++){
    int i = tid + t*256;
    const float4 w = *(const float4*)(cw + (size_t)o*4096 + (size_t)i*4);
    acc += (w.x + w.y + w.z + w.w) * in_b[i];
  }
  for (int off = 32; off; off >>= 1) acc += __shfl_down(acc, off);
  __shared__ float ls[4];
  if ((tid & 63) == 0) ls[tid >> 6] = acc;
  __syncthreads();
  if (tid == 0) cb2[o] = conv_b[o] + ls[0] + ls[1] + ls[2] + ls[3];
}

// ---------------- MFMA GEMM: C[m,n] = epi( sum_k A[m,k]*B[n,k] + bias[n] ) -------------
#define TBK 64

template<int EPI, int CONV, int NFRAG>
__launch_bounds__(256)
__global__ void mfma_gemm(const bf16* __restrict__ A, int lda,
                          const bf16* __restrict__ B, int ldb,
                          const float* __restrict__ bias,
                          float* __restrict__ outF,
                          bf16* __restrict__ outB0,
                          int ldo, int K, int azs, int ozs, int kzs)
{
  __shared__ bf16 As[128*TBK];           // 16 KB
  __shared__ bf16 Bs[32*NFRAG*TBK];      // 4/8 KB
  const int tid  = threadIdx.x;
  const int lane = tid & 63;
  const int wave = tid >> 6;
  const int wr = (wave >> 1) * 64;
  const int wc = (wave & 1) * 16 * NFRAG;
  const int mBase = blockIdx.x * 128;
  const int nBase = blockIdx.y * (32*NFRAG);
  A += (size_t)blockIdx.z * azs;
  const int nOff = blockIdx.z * ozs;
  const int koff = blockIdx.z * kzs;

  f32x4 acc[4][NFRAG] = {};

  for (int k0 = 0; k0 < K; k0 += TBK) {
    __syncthreads();
    #pragma unroll
    for (int it = 0; it < 4; it++) {      // As: 1024 chunks of 16B
      const int idx = it*256 + tid;
      const int r = idx >> 3, c16 = idx & 7;
      const bf16* ga;
      if (CONV) {
        const int tap = k0 >> 9, kk = k0 & 511;
        const int m = mBase + r;
        const int cc = m >> 8;
        int p = (m & 255) + tap - 2;
        p = min(max(p, 0), PP-1);
        ga = A + ((size_t)(cc*PP + p))*DMH + kk + c16*8;
      } else {
        ga = A + (size_t)(mBase + r)*lda + koff + k0 + c16*8;
      }
      g2l16(ga, &As[(size_t)idx*8]);
    }
    #pragma unroll
    for (int it = 0; it < NFRAG; it++) {  // Bs: 256*NFRAG chunks of 16B
      const int idx = it*256 + tid;
      const int r = idx >> 3, c16 = idx & 7;
      const bf16* gb = B + (size_t)(nBase + r)*ldb + koff + k0 + c16*8;
      g2l16(gb, &Bs[(size_t)idx*8]);
    }
    __syncthreads();
    #pragma unroll
    for (int ks = 0; ks < 2; ks++) {
      bf16x8 af[4], bfr[NFRAG];
      #pragma unroll
      for (int r = 0; r < 4; r++)
        af[r] = *(const bf16x8*)&As[(wr + r*16 + (lane & 15))*TBK + ks*32 + (lane>>4)*8];
      #pragma unroll
      for (int c = 0; c < NFRAG; c++)
        bfr[c] = *(const bf16x8*)&Bs[(wc + c*16 + (lane & 15))*TBK + ks*32 + (lane>>4)*8];
      #pragma unroll
      for (int r = 0; r < 4; r++)
        #pragma unroll
        for (int c = 0; c < NFRAG; c++)
          acc[r][c] = __builtin_amdgcn_mfma_f32_16x16x32_bf16(af[r], bfr[c], acc[r][c], 0, 0, 0);
    }
  }

  const int col0 = lane & 15;
  const int row0 = (lane >> 4) * 4;
  #pragma unroll
  for (int r = 0; r < 4; r++) {
    #pragma unroll
    for (int c = 0; c < NFRAG; c++) {
      #pragma unroll
      for (int reg = 0; reg < 4; reg++) {
        const int m = mBase + wr + r*16 + row0 + reg;
        const int n = nBase + wc + c*16 + col0;
        const float av = acc[r][c][reg];
        if (EPI == 0) {
          outF[(size_t)m*ldo + n] = av + bias[n];
        } else if (EPI == 1) {
          outB0[(size_t)m*ldo + n] = f2b(geluf(av + bias[n]));
        } else if (EPI == 2) {
          outB0[(size_t)m*ldo + n] = f2b(geluf(geluf(av + bias[n])));
        } else if (EPI == 3) {
          outB0[(size_t)m*ldo + n + nOff] = f2b(av);
        } else {
          const float vv = av + ((blockIdx.z == 0) ? bias[n] : 0.0f);
          atomicAdd(&outF[(size_t)m*ldo + n], vv);
        }
      }
    }
  }
}

// ---------------- dt GEMM (K=32) + pack {dt fp32 | xi bf16 | gz bf16} -> pk ----------
__launch_bounds__(256)
__global__ void dt_pack(const float* __restrict__ xdb,   // [M,64], cols 0..31 = dt_raw
                        const float* __restrict__ dt_w,  // [DIH,32]
                        const float* __restrict__ dt_b,  // [DIH]
                        const bf16* __restrict__ xi,     // [M,DIH]
                        const bf16* __restrict__ gz,     // [M,DIH]
                        uint2* __restrict__ pk)          // [M,DIH]
{
  __shared__ float As[64][36];   // +4 pad
  __shared__ float Bw[64][36];
  const int tid = threadIdx.x;
  const int m0 = blockIdx.x * 64;
  const int d0 = blockIdx.y * 64;
  {
    #pragma unroll
    for (int t = 0; t < 2; t++){
      int q = tid*2 + t;            // 512 float4 per matrix
      int r = q >> 3, c4 = (q & 7)*4;
      *(float4*)&As[r][c4] = *(const float4*)&xdb[(size_t)(m0+r)*64 + c4];
      *(float4*)&Bw[r][c4] = *(const float4*)&dt_w[(size_t)(d0+r)*NDT + c4];
    }
  }
  __syncthreads();
  const int tx = tid & 15, ty = tid >> 4;
  float acc[4][4];
  #pragma unroll
  for (int i = 0; i < 4; i++)
    #pragma unroll
    for (int j = 0; j < 4; j++) acc[i][j] = dt_b[d0 + tx*4 + j];
  #pragma unroll
  for (int k = 0; k < 32; k += 4){
    float4 a4[4], b4[4];
    #pragma unroll
    for (int i = 0; i < 4; i++) a4[i] = *(const float4*)&As[ty*4+i][k];
    #pragma unroll
    for (int j = 0; j < 4; j++) b4[j] = *(const float4*)&Bw[tx*4+j][k];
    #pragma unroll
    for (int i = 0; i < 4; i++)
      #pragma unroll
      for (int j = 0; j < 4; j++)
        acc[i][j] += a4[i].x*b4[j].x + a4[i].y*b4[j].y + a4[i].z*b4[j].z + a4[i].w*b4[j].w;
  }
  #pragma unroll
  for (int i = 0; i < 4; i++){
    const int m = m0 + ty*4 + i;
    const int d = d0 + tx*4;
    const ushort4 xh = *(const ushort4*)((const ushort*)xi + (size_t)m*DIH + d);
    const ushort4 gh = *(const ushort4*)((const ushort*)gz + (size_t)m*DIH + d);
    const ushort xs[4] = {xh.x, xh.y, xh.z, xh.w};
    const ushort gs[4] = {gh.x, gh.y, gh.z, gh.w};
    uint2 o[4];
    #pragma unroll
    for (int j = 0; j < 4; j++){
      o[j].x = __float_as_uint(softplusf(acc[i][j]));
      o[j].y = (uint)xs[j] | ((uint)gs[j] << 16);
    }
    *(uint4*)&pk[(size_t)m*DIH + d]     = *(uint4*)&o[0];
    *(uint4*)&pk[(size_t)m*DIH + d + 2] = *(uint4*)&o[2];
  }
}

// ---------------- chunked selective scan (coalesced layout) ----------------
// block = 16 dl x 16 n, d = blockIdx.y*16 + dl varies across lanes -> per step a
// block touches pk[m, dg*16..+15] = one full cacheline. n = tid&15 keeps the
// shfl_xor(1,2,4,8) reduction within a wave. AS/sIn laid out [c][dg][g][tid].
__launch_bounds__(256)
__global__ void scan_a(const uint2* __restrict__ pk, const float* __restrict__ xdb,
                       const float* __restrict__ A_log, float2* __restrict__ AS)
{
  const int g = blockIdx.x, dg = blockIdx.y, c = blockIdx.z;
  const int tid = threadIdx.x;
  const int n = tid & 15, dl = tid >> 4;
  const int d = dg*16 + dl;
  const int m0 = c*PP + g*16;
  const float a = -__expf(A_log[(size_t)d*NST + n]);
  const uint2* qp = pk + (size_t)m0*DIH + d;
  const float* bp = xdb + (size_t)m0*64 + 32 + n;
  uint2 q[16]; float Bv[16];
  #pragma unroll
  for (int j = 0; j < 16; j++){ q[j] = qp[(size_t)j*DIH]; Bv[j] = bp[j*64]; }
  float s = 0.f, Ap = 1.f;
  #pragma unroll
  for (int j = 0; j < 16; j++){
    const float dtv = __uint_as_float(q[j].x);
    bf16 xh; *(ushort*)&xh = (ushort)(q[j].y & 0xffffu);
    const float e = __expf(dtv*a);
    s = s*e + (dtv*b2f(xh))*Bv[j];
    Ap *= e;
  }
  float2 o; o.x = Ap; o.y = s;
  AS[(((size_t)(c*64+dg))*16 + g)*256 + tid] = o;
}

__launch_bounds__(256)
__global__ void scan_b(const float2* __restrict__ AS, const float* __restrict__ s0,
                       float* __restrict__ sIn)
{
  const int dg = blockIdx.x, c = blockIdx.y;
  const int tid = threadIdx.x;
  const int n = tid & 15, dl = tid >> 4;
  const int d = dg*16 + dl;
  float s = s0[((size_t)c*DIH + d)*NST + n];
  const size_t base = (((size_t)(c*64+dg))*16)*256 + tid;
  float2 f[16];
  #pragma unroll
  for (int g = 0; g < 16; g++) f[g] = AS[base + g*256];
  #pragma unroll
  for (int g = 0; g < 16; g++){
    sIn[base + g*256] = s;
    s = f[g].y + f[g].x*s;
  }
}

__launch_bounds__(256)
__global__ void scan_c(const uint2* __restrict__ pk, const float* __restrict__ xdb,
                       const float* __restrict__ A_log, const float* __restrict__ Dp,
                       const float* __restrict__ sIn,
                       bf16* __restrict__ ypre, float* __restrict__ state_out)
{
  const int g = blockIdx.x, dg = blockIdx.y, c = blockIdx.z;
  const int tid = threadIdx.x;
  const int n = tid & 15, dl = tid >> 4;
  const int d = dg*16 + dl;
  const int m0 = c*PP + g*16;
  const float a = -__expf(A_log[(size_t)d*NST + n]);
  const float Dv = Dp[d];
  const uint2* qp = pk + (size_t)m0*DIH + d;
  const float* bp = xdb + (size_t)m0*64 + 32 + n;
  const float* cp = bp + NST;
  uint2 q[16]; float Bv[16], Cv[16];
  #pragma unroll
  for (int j = 0; j < 16; j++){
    q[j] = qp[(size_t)j*DIH]; Bv[j] = bp[j*64]; Cv[j] = cp[j*64];
  }
  float s = sIn[(((size_t)(c*64+dg))*16 + g)*256 + tid];
  __shared__ ushort yb[16][16];
  #pragma unroll
  for (int j = 0; j < 16; j++){
    const float dtv = __uint_as_float(q[j].x);
    bf16 xh; *(ushort*)&xh = (ushort)(q[j].y & 0xffffu);
    bf16 gh; *(ushort*)&gh = (ushort)(q[j].y >> 16);
    const float xiv = b2f(xh);
    const float e = __expf(dtv*a);
    s = s*e + (dtv*xiv)*Bv[j];
    float y = s*Cv[j];
    y += __shfl_xor(y, 1);
    y += __shfl_xor(y, 2);
    y += __shfl_xor(y, 4);
    y += __shfl_xor(y, 8);
    if (n == 0){
      bf16 h = f2b((y + Dv*xiv) * b2f(gh));
      yb[j][dl] = *(const ushort*)&h;
    }
  }
  __syncthreads();
  if (tid < 32){
    const int j = tid >> 1, half = tid & 1;
    ushort* dst = (ushort*)ypre + (size_t)(m0 + j)*DIH + dg*16 + half*8;
    *(uint4*)dst = *(const uint4*)&yb[j][half*8];
  }
  if (g == 15) state_out[((size_t)c*DIH + d)*NST + n] = s;
}

extern "C" void kernel_launch(void* const* d_in, const int* in_sizes, int n_in,
                              void* d_out, int out_size, void* d_ws, size_t ws_size,
                              hipStream_t stream) {
  const float* x       = (const float*)d_in[0];
  const float* s0      = (const float*)d_in[1];
  const float* in_w    = (const float*)d_in[2];
  const float* in_b    = (const float*)d_in[3];
  const float* conv_w  = (const float*)d_in[4];
  const float* conv_b  = (const float*)d_in[5];
  const float* param_w = (const float*)d_in[6];
  const float* param_b = (const float*)d_in[7];
  const float* dt_w    = (const float*)d_in[8];
  const float* dt_b    = (const float*)d_in[9];
  const float* out_w   = (const float*)d_in[10];
  const float* out_b   = (const float*)d_in[11];
  const float* A_log   = (const float*)d_in[12];
  const float* Dp      = (const float*)d_in[13];

  char* ws = (char*)d_ws;
  uint2*  pk    = (uint2*)ws;  ws += (size_t)MM*DIH*8;     // 32 MB
  float*  xdb   = (float*)ws;  ws += (size_t)MM*64*4;      //  1 MB
  float*  cb2   = (float*)ws;  ws += 4096;                 //  4 KB
  bf16*   ypre  = (bf16*)ws;   ws += (size_t)MM*DIH*2;     //  8 MB
  bf16*   outwb = (bf16*)ws;   ws += (size_t)DMH*DIH*2;    //  1 MB
  bf16*   pwb   = (bf16*)ws;   ws += (size_t)64*DIH*2;     // 128 KB
  char*   U     = ws;          ws += (size_t)48*1024*1024; // union region, 48 MB
  // early-phase tenants of U (all dead before scan_a):
  bf16* xi   = (bf16*)(U);
  bf16* gz   = (bf16*)(U + (size_t) 8*1024*1024);
  bf16* Wfb  = (bf16*)(U + (size_t)16*1024*1024);
  bf16* xbf  = (bf16*)(U + (size_t)20*1024*1024);
  bf16* inwz = (bf16*)(U + (size_t)24*1024*1024);
  bf16* inwT = (bf16*)(U + (size_t)25*1024*1024);
  bf16* cwT  = (bf16*)(U + (size_t)26*1024*1024);
  // scan-phase tenants of U (xi/gz dead after dt_pack):
  float2* AS  = (float2*)(U);                              // 32 MB
  float*  sIn = (float*)(U + (size_t)32*1024*1024);        // 16 MB

  float* y_out  = (float*)d_out;                           // [C,P,DM] fp32
  float* st_out = y_out + (size_t)MM*DMH;                  // [C,DI,16] fp32

  // casts / repacks / fold prep
  f32_to_bf16<<<MM*DMH/4/256, 256, 0, stream>>>(x, xbf, MM*DMH/4);
  f32_to_bf16<<<DIH*DMH/4/256, 256, 0, stream>>>(in_w + (size_t)DIH*DMH, inwz, DIH*DMH/4);
  f32_to_bf16<<<DMH*DIH/4/256, 256, 0, stream>>>(out_w, outwb, DMH*DIH/4);
  f32_to_bf16<<<64*DIH/4/256, 256, 0, stream>>>(param_w, pwb, 64*DIH/4);
  repack_cw<<<DIH*DIH/256, 256, 0, stream>>>(conv_w, cwT);
  tr_inw<<<DMH*DIH/256, 256, 0, stream>>>(in_w, inwT);
  fold_bias<<<DIH, 256, 0, stream>>>(conv_w, in_b, conv_b, cb2);
  zerof4<<<MM*64/4/256, 256, 0, stream>>>((float4*)xdb, MM*64/4);

  // fold: Wf[k][o][m] = sum_i conv_w[o,i,k]*in_w[i,m]   (4 taps via grid.z)
  mfma_gemm<3,0,2><<<dim3(DIH/128, DMH/64, 4), 256, 0, stream>>>(
      cwT, DIH, inwT, DIH, nullptr, nullptr, Wfb, 4*DMH, DIH, DIH*DIH, DMH, 0);
  // z-half in_proj: gelu(gelu(x @ in_w_z^T + b_z)) -> gz (contiguous bf16)
  mfma_gemm<2,0,2><<<dim3(MM/128, DIH/64), 256, 0, stream>>>(
      xbf, DMH, inwz, DMH, in_b + DIH, nullptr, gz, DIH, DMH, 0, 0, 0);
  // fused conv: gelu( sum_tap x[clamp] @ Wf_tap^T + cb2 ) -> xi (contiguous bf16)
  mfma_gemm<1,1,2><<<dim3(MM/128, DIH/64), 256, 0, stream>>>(
      xbf, DMH, Wfb, 4*DMH, cb2, nullptr, xi, DIH, 4*DMH, 0, 0, 0);
  // x_db = xi @ param_w.T + param_b   (MFMA split-K=8, fp32 atomics into zeroed xdb)
  mfma_gemm<4,0,2><<<dim3(MM/128, 1, 8), 256, 0, stream>>>(
      xi, DIH, pwb, DIH, param_b, xdb, nullptr, 64, 128, 0, 0, 128);
  // dt = softplus(x_db[:,:32] @ dt_w.T + dt_b), pack {dt|xi|gz} -> pk (coalesced)
  dt_pack<<<dim3(MM/64, DIH/64), 256, 0, stream>>>(xdb, dt_w, dt_b, xi, gz, pk);
  // chunked scan, d-across-lanes layout
  scan_a<<<dim3(16, 64, CC), 256, 0, stream>>>(pk, xdb, A_log, AS);
  scan_b<<<dim3(64, CC), 256, 0, stream>>>(AS, s0, sIn);
  scan_c<<<dim3(16, 64, CC), 256, 0, stream>>>(pk, xdb, A_log, Dp, sIn, ypre, st_out);
  // out projection
  mfma_gemm<0,0,1><<<dim3(MM/128, DMH/32), 256, 0, stream>>>(
      ypre, DIH, outwb, DIH, out_b, y_out, nullptr, DMH, DIH, 0, 0, 0);
}

// Round 10
// 328.553 us; speedup vs baseline: 1.2339x; 1.1373x over previous
//
#include <hip/hip_runtime.h>
#include <hip/hip_bf16.h>

typedef __hip_bfloat16 bf16;
typedef short bf16x8 __attribute__((ext_vector_type(8)));
typedef float f32x4 __attribute__((ext_vector_type(4)));

#define CC 16
#define PP 256
#define DMH 512
#define DIH 1024
#define MM (CC*PP)   /* 4096 rows (c,p) */
#define NST 16
#define NDT 32

__device__ __forceinline__ float b2f(bf16 v){ return __bfloat162float(v); }
__device__ __forceinline__ bf16  f2b(float v){ return __float2bfloat16(v); }

__device__ __forceinline__ float geluf(float x){
  float x3 = x*x*x;
  return 0.5f*x*(1.0f + tanhf(0.7978845608028654f*x + 0.035677408136300125f*x3));
}
__device__ __forceinline__ float softplusf(float x){
  if (x > 20.0f) return x;
  return log1pf(expf(x));
}

__device__ __forceinline__ void g2l16(const bf16* g, bf16* l){
  __builtin_amdgcn_global_load_lds(
      (const __attribute__((address_space(1))) void*)g,
      (__attribute__((address_space(3))) void*)(uint32_t)(uintptr_t)l,
      16, 0, 0);
}

// sum over the 16 lanes of a DPP row; result valid at lane (row_base+15)
__device__ __forceinline__ float row_sum16(float y){
  int t;
  t = __builtin_amdgcn_update_dpp(0, __float_as_int(y), 0x111, 0xf, 0xf, true); // row_shr:1
  y += __int_as_float(t);
  t = __builtin_amdgcn_update_dpp(0, __float_as_int(y), 0x112, 0xf, 0xf, true); // row_shr:2
  y += __int_as_float(t);
  t = __builtin_amdgcn_update_dpp(0, __float_as_int(y), 0x114, 0xf, 0xf, true); // row_shr:4
  y += __int_as_float(t);
  t = __builtin_amdgcn_update_dpp(0, __float_as_int(y), 0x118, 0xf, 0xf, true); // row_shr:8
  y += __int_as_float(t);
  return y;
}

// ---------------- fused prep: casts + conv repack + in_w transpose + xdb zero ---------
// block ranges: [0,2048) xbf | [2048,2560) inwz | [2560,3072) outwb | [3072,3136) pwb
//               [3136,7232) cwT repack | [7232,9280) tr_inw | [9280,9536) zero xdb
__global__ void prep_all(const float* __restrict__ x, const float* __restrict__ in_w,
                         const float* __restrict__ out_w, const float* __restrict__ param_w,
                         const float* __restrict__ conv_w,
                         bf16* __restrict__ xbf, bf16* __restrict__ inwz,
                         bf16* __restrict__ outwb, bf16* __restrict__ pwb,
                         bf16* __restrict__ cwT, bf16* __restrict__ inwT,
                         float4* __restrict__ xdb4)
{
  const int b = blockIdx.x, tid = threadIdx.x;
  if (b < 3136){
    const float* src; bf16* dst; int i;
    if (b < 2048)      { src = x;                       dst = xbf;   i = b*256 + tid; }
    else if (b < 2560) { src = in_w + (size_t)DIH*DMH;  dst = inwz;  i = (b-2048)*256 + tid; }
    else if (b < 3072) { src = out_w;                   dst = outwb; i = (b-2560)*256 + tid; }
    else               { src = param_w;                 dst = pwb;   i = (b-3072)*256 + tid; }
    float4 v = ((const float4*)src)[i];
    bf16 o[4] = {f2b(v.x), f2b(v.y), f2b(v.z), f2b(v.w)};
    *(ushort4*)&dst[(size_t)i*4] = *(const ushort4*)o;
  } else if (b < 7232){
    const size_t idx = (size_t)(b-3136)*256 + tid;      // o*1024 + i
    const float4 v = *(const float4*)(conv_w + idx*4);  // [o][i][tap] -> [tap][o][i]
    cwT[idx]                     = f2b(v.x);
    cwT[(size_t)DIH*DIH   + idx] = f2b(v.y);
    cwT[(size_t)2*DIH*DIH + idx] = f2b(v.z);
    cwT[(size_t)3*DIH*DIH + idx] = f2b(v.w);
  } else if (b < 9280){
    int t = (b-7232)*256 + tid;                         // in_w xi-half [i][m] -> [m][i]
    int m = t >> 10, i = t & 1023;
    inwT[t] = f2b(in_w[(size_t)i*DMH + m]);
  } else {
    xdb4[(b-9280)*256 + tid] = make_float4(0.f,0.f,0.f,0.f);
  }
}

// cb2[o] = conv_b[o] + sum_i (sum_k conv_w[o,i,k]) * in_b[i]
__global__ void fold_bias(const float* __restrict__ cw, const float* __restrict__ in_b,
                          const float* __restrict__ conv_b, float* __restrict__ cb2){
  const int o = blockIdx.x;
  const int tid = threadIdx.x;
  float acc = 0.0f;
  #pragma unroll
  for (int t = 0; t < 4; t++){
    int i = tid + t*256;
    const float4 w = *(const float4*)(cw + (size_t)o*4096 + (size_t)i*4);
    acc += (w.x + w.y + w.z + w.w) * in_b[i];
  }
  for (int off = 32; off; off >>= 1) acc += __shfl_down(acc, off);
  __shared__ float ls[4];
  if ((tid & 63) == 0) ls[tid >> 6] = acc;
  __syncthreads();
  if (tid == 0) cb2[o] = conv_b[o] + ls[0] + ls[1] + ls[2] + ls[3];
}

// ---------------- MFMA GEMM: C[m,n] = epi( sum_k A[m,k]*B[n,k] + bias[n] ) -------------
#define TBK 64

template<int EPI, int CONV, int NFRAG>
__launch_bounds__(256)
__global__ void mfma_gemm(const bf16* __restrict__ A, int lda,
                          const bf16* __restrict__ B, int ldb,
                          const float* __restrict__ bias,
                          float* __restrict__ outF,
                          bf16* __restrict__ outB0,
                          int ldo, int K, int azs, int ozs, int kzs)
{
  __shared__ bf16 As[128*TBK];           // 16 KB
  __shared__ bf16 Bs[32*NFRAG*TBK];      // 4/8 KB
  const int tid  = threadIdx.x;
  const int lane = tid & 63;
  const int wave = tid >> 6;
  const int wr = (wave >> 1) * 64;
  const int wc = (wave & 1) * 16 * NFRAG;
  const int mBase = blockIdx.x * 128;
  const int nBase = blockIdx.y * (32*NFRAG);
  A += (size_t)blockIdx.z * azs;
  const int nOff = blockIdx.z * ozs;
  const int koff = blockIdx.z * kzs;

  f32x4 acc[4][NFRAG] = {};

  for (int k0 = 0; k0 < K; k0 += TBK) {
    __syncthreads();
    #pragma unroll
    for (int it = 0; it < 4; it++) {      // As: 1024 chunks of 16B
      const int idx = it*256 + tid;
      const int r = idx >> 3, c16 = idx & 7;
      const bf16* ga;
      if (CONV) {
        const int tap = k0 >> 9, kk = k0 & 511;
        const int m = mBase + r;
        const int cc = m >> 8;
        int p = (m & 255) + tap - 2;
        p = min(max(p, 0), PP-1);
        ga = A + ((size_t)(cc*PP + p))*DMH + kk + c16*8;
      } else {
        ga = A + (size_t)(mBase + r)*lda + koff + k0 + c16*8;
      }
      g2l16(ga, &As[(size_t)idx*8]);
    }
    #pragma unroll
    for (int it = 0; it < NFRAG; it++) {  // Bs: 256*NFRAG chunks of 16B
      const int idx = it*256 + tid;
      const int r = idx >> 3, c16 = idx & 7;
      const bf16* gb = B + (size_t)(nBase + r)*ldb + koff + k0 + c16*8;
      g2l16(gb, &Bs[(size_t)idx*8]);
    }
    __syncthreads();
    #pragma unroll
    for (int ks = 0; ks < 2; ks++) {
      bf16x8 af[4], bfr[NFRAG];
      #pragma unroll
      for (int r = 0; r < 4; r++)
        af[r] = *(const bf16x8*)&As[(wr + r*16 + (lane & 15))*TBK + ks*32 + (lane>>4)*8];
      #pragma unroll
      for (int c = 0; c < NFRAG; c++)
        bfr[c] = *(const bf16x8*)&Bs[(wc + c*16 + (lane & 15))*TBK + ks*32 + (lane>>4)*8];
      #pragma unroll
      for (int r = 0; r < 4; r++)
        #pragma unroll
        for (int c = 0; c < NFRAG; c++)
          acc[r][c] = __builtin_amdgcn_mfma_f32_16x16x32_bf16(af[r], bfr[c], acc[r][c], 0, 0, 0);
    }
  }

  const int col0 = lane & 15;
  const int row0 = (lane >> 4) * 4;
  #pragma unroll
  for (int r = 0; r < 4; r++) {
    #pragma unroll
    for (int c = 0; c < NFRAG; c++) {
      #pragma unroll
      for (int reg = 0; reg < 4; reg++) {
        const int m = mBase + wr + r*16 + row0 + reg;
        const int n = nBase + wc + c*16 + col0;
        const float av = acc[r][c][reg];
        if (EPI == 0) {
          outF[(size_t)m*ldo + n] = av + bias[n];
        } else if (EPI == 1) {
          outB0[(size_t)m*ldo + n] = f2b(geluf(av + bias[n]));
        } else if (EPI == 2) {
          outB0[(size_t)m*ldo + n] = f2b(geluf(geluf(av + bias[n])));
        } else if (EPI == 3) {
          outB0[(size_t)m*ldo + n + nOff] = f2b(av);
        } else {
          const float vv = av + ((blockIdx.z == 0) ? bias[n] : 0.0f);
          atomicAdd(&outF[(size_t)m*ldo + n], vv);
        }
      }
    }
  }
}

// ---------------- dt GEMM (K=32) + pack {dt fp32 | xi bf16 | gz bf16} -> pk ----------
__launch_bounds__(256)
__global__ void dt_pack(const float* __restrict__ xdb,   // [M,64], cols 0..31 = dt_raw
                        const float* __restrict__ dt_w,  // [DIH,32]
                        const float* __restrict__ dt_b,  // [DIH]
                        const bf16* __restrict__ xi,     // [M,DIH]
                        const bf16* __restrict__ gz,     // [M,DIH]
                        uint2* __restrict__ pk)          // [M,DIH]
{
  __shared__ float As[64][36];   // +4 pad
  __shared__ float Bw[64][36];
  const int tid = threadIdx.x;
  const int m0 = blockIdx.x * 64;
  const int d0 = blockIdx.y * 64;
  {
    #pragma unroll
    for (int t = 0; t < 2; t++){
      int q = tid*2 + t;            // 512 float4 per matrix
      int r = q >> 3, c4 = (q & 7)*4;
      *(float4*)&As[r][c4] = *(const float4*)&xdb[(size_t)(m0+r)*64 + c4];
      *(float4*)&Bw[r][c4] = *(const float4*)&dt_w[(size_t)(d0+r)*NDT + c4];
    }
  }
  __syncthreads();
  const int tx = tid & 15, ty = tid >> 4;
  float acc[4][4];
  #pragma unroll
  for (int i = 0; i < 4; i++)
    #pragma unroll
    for (int j = 0; j < 4; j++) acc[i][j] = dt_b[d0 + tx*4 + j];
  #pragma unroll
  for (int k = 0; k < 32; k += 4){
    float4 a4[4], b4[4];
    #pragma unroll
    for (int i = 0; i < 4; i++) a4[i] = *(const float4*)&As[ty*4+i][k];
    #pragma unroll
    for (int j = 0; j < 4; j++) b4[j] = *(const float4*)&Bw[tx*4+j][k];
    #pragma unroll
    for (int i = 0; i < 4; i++)
      #pragma unroll
      for (int j = 0; j < 4; j++)
        acc[i][j] += a4[i].x*b4[j].x + a4[i].y*b4[j].y + a4[i].z*b4[j].z + a4[i].w*b4[j].w;
  }
  #pragma unroll
  for (int i = 0; i < 4; i++){
    const int m = m0 + ty*4 + i;
    const int d = d0 + tx*4;
    const ushort4 xh = *(const ushort4*)((const ushort*)xi + (size_t)m*DIH + d);
    const ushort4 gh = *(const ushort4*)((const ushort*)gz + (size_t)m*DIH + d);
    const ushort xs[4] = {xh.x, xh.y, xh.z, xh.w};
    const ushort gs[4] = {gh.x, gh.y, gh.z, gh.w};
    uint2 o[4];
    #pragma unroll
    for (int j = 0; j < 4; j++){
      o[j].x = __float_as_uint(softplusf(acc[i][j]));
      o[j].y = (uint)xs[j] | ((uint)gs[j] << 16);
    }
    *(uint4*)&pk[(size_t)m*DIH + d]     = *(uint4*)&o[0];
    *(uint4*)&pk[(size_t)m*DIH + d + 2] = *(uint4*)&o[2];
  }
}

// ---------------- chunked selective scan (LDS pk tile + DPP reduction) ----------------
// block = 16 dl x 16 n; d = dg*16+dl across lanes. pk tile (16 steps x 16 d, 2 KB)
// staged via one coalesced load per thread; in-loop pk access is a broadcast
// ds_read_b64. y reduced over 16 n-lanes with 4 DPP row_shr adds (lands at n=15).
__launch_bounds__(256)
__global__ void scan_a(const uint2* __restrict__ pk, const float* __restrict__ xdb,
                       const float* __restrict__ A_log, float2* __restrict__ AS)
{
  const int g = blockIdx.x, dg = blockIdx.y, c = blockIdx.z;
  const int tid = threadIdx.x;
  const int n = tid & 15, dl = tid >> 4;
  const int d = dg*16 + dl;
  const int m0 = c*PP + g*16;
  __shared__ uint2 pkT[16][16];   // [j][dl]
  {
    const int j = tid >> 4, dd = tid & 15;
    pkT[j][dd] = pk[(size_t)(m0 + j)*DIH + dg*16 + dd];
  }
  const float a = -__expf(A_log[(size_t)d*NST + n]);
  const float* bp = xdb + (size_t)m0*64 + 32 + n;
  float Bv[16];
  #pragma unroll
  for (int j = 0; j < 16; j++) Bv[j] = bp[j*64];
  __syncthreads();
  float s = 0.f, Ap = 1.f;
  #pragma unroll
  for (int j = 0; j < 16; j++){
    const uint2 q = pkT[j][dl];
    const float dtv = __uint_as_float(q.x);
    bf16 xh; *(ushort*)&xh = (ushort)(q.y & 0xffffu);
    const float e = __expf(dtv*a);
    s = s*e + (dtv*b2f(xh))*Bv[j];
    Ap *= e;
  }
  float2 o; o.x = Ap; o.y = s;
  AS[(((size_t)(c*64+dg))*16 + g)*256 + tid] = o;
}

__launch_bounds__(256)
__global__ void scan_b(const float2* __restrict__ AS, const float* __restrict__ s0,
                       float* __restrict__ sIn)
{
  const int dg = blockIdx.x, c = blockIdx.y;
  const int tid = threadIdx.x;
  const int n = tid & 15, dl = tid >> 4;
  const int d = dg*16 + dl;
  float s = s0[((size_t)c*DIH + d)*NST + n];
  const size_t base = (((size_t)(c*64+dg))*16)*256 + tid;
  float2 f[16];
  #pragma unroll
  for (int g = 0; g < 16; g++) f[g] = AS[base + g*256];
  #pragma unroll
  for (int g = 0; g < 16; g++){
    sIn[base + g*256] = s;
    s = f[g].y + f[g].x*s;
  }
}

__launch_bounds__(256)
__global__ void scan_c(const uint2* __restrict__ pk, const float* __restrict__ xdb,
                       const float* __restrict__ A_log, const float* __restrict__ Dp,
                       const float* __restrict__ sIn,
                       bf16* __restrict__ ypre, float* __restrict__ state_out)
{
  const int g = blockIdx.x, dg = blockIdx.y, c = blockIdx.z;
  const int tid = threadIdx.x;
  const int n = tid & 15, dl = tid >> 4;
  const int d = dg*16 + dl;
  const int m0 = c*PP + g*16;
  __shared__ uint2 pkT[16][16];   // [j][dl]
  {
    const int j = tid >> 4, dd = tid & 15;
    pkT[j][dd] = pk[(size_t)(m0 + j)*DIH + dg*16 + dd];
  }
  const float a = -__expf(A_log[(size_t)d*NST + n]);
  const float Dv = Dp[d];
  const float* bp = xdb + (size_t)m0*64 + 32 + n;
  const float* cp = bp + NST;
  float Bv[16], Cv[16];
  #pragma unroll
  for (int j = 0; j < 16; j++){ Bv[j] = bp[j*64]; Cv[j] = cp[j*64]; }
  float s = sIn[(((size_t)(c*64+dg))*16 + g)*256 + tid];
  __shared__ ushort yb[16][16];
  __syncthreads();
  #pragma unroll
  for (int j = 0; j < 16; j++){
    const uint2 q = pkT[j][dl];
    const float dtv = __uint_as_float(q.x);
    bf16 xh; *(ushort*)&xh = (ushort)(q.y & 0xffffu);
    bf16 gh; *(ushort*)&gh = (ushort)(q.y >> 16);
    const float xiv = b2f(xh);
    const float e = __expf(dtv*a);
    s = s*e + (dtv*xiv)*Bv[j];
    float y = row_sum16(s*Cv[j]);          // valid at n==15
    if (n == 15){
      bf16 h = f2b((y + Dv*xiv) * b2f(gh));
      yb[j][dl] = *(const ushort*)&h;
    }
  }
  __syncthreads();
  if (tid < 32){
    const int j = tid >> 1, half = tid & 1;
    ushort* dst = (ushort*)ypre + (size_t)(m0 + j)*DIH + dg*16 + half*8;
    *(uint4*)dst = *(const uint4*)&yb[j][half*8];
  }
  if (g == 15) state_out[((size_t)c*DIH + d)*NST + n] = s;
}

extern "C" void kernel_launch(void* const* d_in, const int* in_sizes, int n_in,
                              void* d_out, int out_size, void* d_ws, size_t ws_size,
                              hipStream_t stream) {
  const float* x       = (const float*)d_in[0];
  const float* s0      = (const float*)d_in[1];
  const float* in_w    = (const float*)d_in[2];
  const float* in_b    = (const float*)d_in[3];
  const float* conv_w  = (const float*)d_in[4];
  const float* conv_b  = (const float*)d_in[5];
  const float* param_w = (const float*)d_in[6];
  const float* param_b = (const float*)d_in[7];
  const float* dt_w    = (const float*)d_in[8];
  const float* dt_b    = (const float*)d_in[9];
  const float* out_w   = (const float*)d_in[10];
  const float* out_b   = (const float*)d_in[11];
  const float* A_log   = (const float*)d_in[12];
  const float* Dp      = (const float*)d_in[13];

  char* ws = (char*)d_ws;
  uint2*  pk    = (uint2*)ws;  ws += (size_t)MM*DIH*8;     // 32 MB
  float*  xdb   = (float*)ws;  ws += (size_t)MM*64*4;      //  1 MB
  float*  cb2   = (float*)ws;  ws += 4096;                 //  4 KB
  bf16*   ypre  = (bf16*)ws;   ws += (size_t)MM*DIH*2;     //  8 MB
  bf16*   outwb = (bf16*)ws;   ws += (size_t)DMH*DIH*2;    //  1 MB
  bf16*   pwb   = (bf16*)ws;   ws += (size_t)64*DIH*2;     // 128 KB
  char*   U     = ws;          ws += (size_t)48*1024*1024; // union region, 48 MB
  // early-phase tenants of U (all dead before scan_a):
  bf16* xi   = (bf16*)(U);
  bf16* gz   = (bf16*)(U + (size_t) 8*1024*1024);
  bf16* Wfb  = (bf16*)(U + (size_t)16*1024*1024);
  bf16* xbf  = (bf16*)(U + (size_t)20*1024*1024);
  bf16* inwz = (bf16*)(U + (size_t)24*1024*1024);
  bf16* inwT = (bf16*)(U + (size_t)25*1024*1024);
  bf16* cwT  = (bf16*)(U + (size_t)26*1024*1024);
  // scan-phase tenants of U (xi/gz dead after dt_pack):
  float2* AS  = (float2*)(U);                              // 32 MB
  float*  sIn = (float*)(U + (size_t)32*1024*1024);        // 16 MB

  float* y_out  = (float*)d_out;                           // [C,P,DM] fp32
  float* st_out = y_out + (size_t)MM*DMH;                  // [C,DI,16] fp32

  // fused prep (casts, conv repack, transpose, xdb zero) + fold_bias
  prep_all<<<9536, 256, 0, stream>>>(x, in_w, out_w, param_w, conv_w,
                                     xbf, inwz, outwb, pwb, cwT, inwT, (float4*)xdb);
  fold_bias<<<DIH, 256, 0, stream>>>(conv_w, in_b, conv_b, cb2);

  // fold: Wf[k][o][m] = sum_i conv_w[o,i,k]*in_w[i,m]   (4 taps via grid.z)
  mfma_gemm<3,0,2><<<dim3(DIH/128, DMH/64, 4), 256, 0, stream>>>(
      cwT, DIH, inwT, DIH, nullptr, nullptr, Wfb, 4*DMH, DIH, DIH*DIH, DMH, 0);
  // z-half in_proj: gelu(gelu(x @ in_w_z^T + b_z)) -> gz (contiguous bf16)
  mfma_gemm<2,0,2><<<dim3(MM/128, DIH/64), 256, 0, stream>>>(
      xbf, DMH, inwz, DMH, in_b + DIH, nullptr, gz, DIH, DMH, 0, 0, 0);
  // fused conv: gelu( sum_tap x[clamp] @ Wf_tap^T + cb2 ) -> xi (contiguous bf16)
  mfma_gemm<1,1,2><<<dim3(MM/128, DIH/64), 256, 0, stream>>>(
      xbf, DMH, Wfb, 4*DMH, cb2, nullptr, xi, DIH, 4*DMH, 0, 0, 0);
  // x_db = xi @ param_w.T + param_b   (MFMA split-K=8, fp32 atomics into zeroed xdb)
  mfma_gemm<4,0,2><<<dim3(MM/128, 1, 8), 256, 0, stream>>>(
      xi, DIH, pwb, DIH, param_b, xdb, nullptr, 64, 128, 0, 0, 128);
  // dt = softplus(x_db[:,:32] @ dt_w.T + dt_b), pack {dt|xi|gz} -> pk (coalesced)
  dt_pack<<<dim3(MM/64, DIH/64), 256, 0, stream>>>(xdb, dt_w, dt_b, xi, gz, pk);
  // chunked scan, d-across-lanes layout, LDS pk tiles + DPP reduction
  scan_a<<<dim3(16, 64, CC), 256, 0, stream>>>(pk, xdb, A_log, AS);
  scan_b<<<dim3(64, CC), 256, 0, stream>>>(AS, s0, sIn);
  scan_c<<<dim3(16, 64, CC), 256, 0, stream>>>(pk, xdb, A_log, Dp, sIn, ypre, st_out);
  // out projection
  mfma_gemm<0,0,1><<<dim3(MM/128, DMH/32), 256, 0, stream>>>(
      ypre, DIH, outwb, DIH, out_b, y_out, nullptr, DMH, DIH, 0, 0, 0);
}

// Round 11
// 324.318 us; speedup vs baseline: 1.2500x; 1.0131x over previous
//
#include <hip/hip_runtime.h>
#include <hip/hip_bf16.h>

typedef __hip_bfloat16 bf16;
typedef short bf16x8 __attribute__((ext_vector_type(8)));
typedef float f32x4 __attribute__((ext_vector_type(4)));

#define CC 16
#define PP 256
#define DMH 512
#define DIH 1024
#define MM (CC*PP)   /* 4096 rows (c,p) */
#define NST 16
#define NDT 32

__device__ __forceinline__ float b2f(bf16 v){ return __bfloat162float(v); }
__device__ __forceinline__ bf16  f2b(float v){ return __float2bfloat16(v); }

__device__ __forceinline__ float geluf(float x){
  float x3 = x*x*x;
  return 0.5f*x*(1.0f + tanhf(0.7978845608028654f*x + 0.035677408136300125f*x3));
}
__device__ __forceinline__ float softplusf(float x){
  if (x > 20.0f) return x;
  return log1pf(expf(x));
}

__device__ __forceinline__ void g2l16(const bf16* g, bf16* l){
  __builtin_amdgcn_global_load_lds(
      (const __attribute__((address_space(1))) void*)g,
      (__attribute__((address_space(3))) void*)(uint32_t)(uintptr_t)l,
      16, 0, 0);
}

// sum over the 16 lanes of a DPP row; result valid at lane (row_base+15)
__device__ __forceinline__ float row_sum16(float y){
  int t;
  t = __builtin_amdgcn_update_dpp(0, __float_as_int(y), 0x111, 0xf, 0xf, true); // row_shr:1
  y += __int_as_float(t);
  t = __builtin_amdgcn_update_dpp(0, __float_as_int(y), 0x112, 0xf, 0xf, true); // row_shr:2
  y += __int_as_float(t);
  t = __builtin_amdgcn_update_dpp(0, __float_as_int(y), 0x114, 0xf, 0xf, true); // row_shr:4
  y += __int_as_float(t);
  t = __builtin_amdgcn_update_dpp(0, __float_as_int(y), 0x118, 0xf, 0xf, true); // row_shr:8
  y += __int_as_float(t);
  return y;
}

// ---------------- fused prep: casts + conv repack + in_w transpose + xdb zero ---------
__global__ void prep_all(const float* __restrict__ x, const float* __restrict__ in_w,
                         const float* __restrict__ out_w, const float* __restrict__ param_w,
                         const float* __restrict__ conv_w,
                         bf16* __restrict__ xbf, bf16* __restrict__ inwz,
                         bf16* __restrict__ outwb, bf16* __restrict__ pwb,
                         bf16* __restrict__ cwT, bf16* __restrict__ inwT,
                         float4* __restrict__ xdb4)
{
  const int b = blockIdx.x, tid = threadIdx.x;
  if (b < 3136){
    const float* src; bf16* dst; int i;
    if (b < 2048)      { src = x;                       dst = xbf;   i = b*256 + tid; }
    else if (b < 2560) { src = in_w + (size_t)DIH*DMH;  dst = inwz;  i = (b-2048)*256 + tid; }
    else if (b < 3072) { src = out_w;                   dst = outwb; i = (b-2560)*256 + tid; }
    else               { src = param_w;                 dst = pwb;   i = (b-3072)*256 + tid; }
    float4 v = ((const float4*)src)[i];
    bf16 o[4] = {f2b(v.x), f2b(v.y), f2b(v.z), f2b(v.w)};
    *(ushort4*)&dst[(size_t)i*4] = *(const ushort4*)o;
  } else if (b < 7232){
    const size_t idx = (size_t)(b-3136)*256 + tid;      // o*1024 + i
    const float4 v = *(const float4*)(conv_w + idx*4);  // [o][i][tap] -> [tap][o][i]
    cwT[idx]                     = f2b(v.x);
    cwT[(size_t)DIH*DIH   + idx] = f2b(v.y);
    cwT[(size_t)2*DIH*DIH + idx] = f2b(v.z);
    cwT[(size_t)3*DIH*DIH + idx] = f2b(v.w);
  } else if (b < 9280){
    int t = (b-7232)*256 + tid;                         // in_w xi-half [i][m] -> [m][i]
    int m = t >> 10, i = t & 1023;
    inwT[t] = f2b(in_w[(size_t)i*DMH + m]);
  } else {
    xdb4[(b-9280)*256 + tid] = make_float4(0.f,0.f,0.f,0.f);
  }
}

// cb2[o] = conv_b[o] + sum_i (sum_k conv_w[o,i,k]) * in_b[i]
__global__ void fold_bias(const float* __restrict__ cw, const float* __restrict__ in_b,
                          const float* __restrict__ conv_b, float* __restrict__ cb2){
  const int o = blockIdx.x;
  const int tid = threadIdx.x;
  float acc = 0.0f;
  #pragma unroll
  for (int t = 0; t < 4; t++){
    int i = tid + t*256;
    const float4 w = *(const float4*)(cw + (size_t)o*4096 + (size_t)i*4);
    acc += (w.x + w.y + w.z + w.w) * in_b[i];
  }
  for (int off = 32; off; off >>= 1) acc += __shfl_down(acc, off);
  __shared__ float ls[4];
  if ((tid & 63) == 0) ls[tid >> 6] = acc;
  __syncthreads();
  if (tid == 0) cb2[o] = conv_b[o] + ls[0] + ls[1] + ls[2] + ls[3];
}

// ---------------- MFMA GEMM: C[m,n] = epi( sum_k A[m,k]*B[n,k] + bias[n] ) -------------
#define TBK 64

template<int EPI, int CONV, int NFRAG>
__launch_bounds__(256)
__global__ void mfma_gemm(const bf16* __restrict__ A, int lda,
                          const bf16* __restrict__ B, int ldb,
                          const float* __restrict__ bias,
                          float* __restrict__ outF,
                          bf16* __restrict__ outB0,
                          int ldo, int K, int azs, int ozs, int kzs)
{
  __shared__ bf16 As[128*TBK];           // 16 KB
  __shared__ bf16 Bs[32*NFRAG*TBK];      // 4/8 KB
  const int tid  = threadIdx.x;
  const int lane = tid & 63;
  const int wave = tid >> 6;
  const int wr = (wave >> 1) * 64;
  const int wc = (wave & 1) * 16 * NFRAG;
  const int mBase = blockIdx.x * 128;
  const int nBase = blockIdx.y * (32*NFRAG);
  A += (size_t)blockIdx.z * azs;
  const int nOff = blockIdx.z * ozs;
  const int koff = blockIdx.z * kzs;

  f32x4 acc[4][NFRAG] = {};

  for (int k0 = 0; k0 < K; k0 += TBK) {
    __syncthreads();
    #pragma unroll
    for (int it = 0; it < 4; it++) {      // As: 1024 chunks of 16B
      const int idx = it*256 + tid;
      const int r = idx >> 3, c16 = idx & 7;
      const bf16* ga;
      if (CONV) {
        const int tap = k0 >> 9, kk = k0 & 511;
        const int m = mBase + r;
        const int cc = m >> 8;
        int p = (m & 255) + tap - 2;
        p = min(max(p, 0), PP-1);
        ga = A + ((size_t)(cc*PP + p))*DMH + kk + c16*8;
      } else {
        ga = A + (size_t)(mBase + r)*lda + koff + k0 + c16*8;
      }
      g2l16(ga, &As[(size_t)idx*8]);
    }
    #pragma unroll
    for (int it = 0; it < NFRAG; it++) {  // Bs: 256*NFRAG chunks of 16B
      const int idx = it*256 + tid;
      const int r = idx >> 3, c16 = idx & 7;
      const bf16* gb = B + (size_t)(nBase + r)*ldb + koff + k0 + c16*8;
      g2l16(gb, &Bs[(size_t)idx*8]);
    }
    __syncthreads();
    #pragma unroll
    for (int ks = 0; ks < 2; ks++) {
      bf16x8 af[4], bfr[NFRAG];
      #pragma unroll
      for (int r = 0; r < 4; r++)
        af[r] = *(const bf16x8*)&As[(wr + r*16 + (lane & 15))*TBK + ks*32 + (lane>>4)*8];
      #pragma unroll
      for (int c = 0; c < NFRAG; c++)
        bfr[c] = *(const bf16x8*)&Bs[(wc + c*16 + (lane & 15))*TBK + ks*32 + (lane>>4)*8];
      #pragma unroll
      for (int r = 0; r < 4; r++)
        #pragma unroll
        for (int c = 0; c < NFRAG; c++)
          acc[r][c] = __builtin_amdgcn_mfma_f32_16x16x32_bf16(af[r], bfr[c], acc[r][c], 0, 0, 0);
    }
  }

  const int col0 = lane & 15;
  const int row0 = (lane >> 4) * 4;
  #pragma unroll
  for (int r = 0; r < 4; r++) {
    #pragma unroll
    for (int c = 0; c < NFRAG; c++) {
      #pragma unroll
      for (int reg = 0; reg < 4; reg++) {
        const int m = mBase + wr + r*16 + row0 + reg;
        const int n = nBase + wc + c*16 + col0;
        const float av = acc[r][c][reg];
        if (EPI == 0) {
          outF[(size_t)m*ldo + n] = av + bias[n];
        } else if (EPI == 1) {
          outB0[(size_t)m*ldo + n] = f2b(geluf(av + bias[n]));
        } else if (EPI == 2) {
          outB0[(size_t)m*ldo + n] = f2b(geluf(geluf(av + bias[n])));
        } else if (EPI == 3) {
          outB0[(size_t)m*ldo + n + nOff] = f2b(av);
        } else {
          const float vv = av + ((blockIdx.z == 0) ? bias[n] : 0.0f);
          atomicAdd(&outF[(size_t)m*ldo + n], vv);
        }
      }
    }
  }
}

// ---------------- chunked selective scan, dt GEMM fused in-block ----------------
// block = 16 dl x 16 n; d = dg*16+dl. Per block: stage xdb[16][64] (dt_raw|B|C),
// dt_w[16][32], xi (and gz) 16x16 tiles; compute dt[j][dl] tile (K=32 dot +
// softplus) in LDS; then the 16-step serial loop reads everything from LDS.
__launch_bounds__(256)
__global__ void scan_a(const float* __restrict__ xdb, const bf16* __restrict__ xi,
                       const float* __restrict__ dt_w, const float* __restrict__ dt_b,
                       const float* __restrict__ A_log, float2* __restrict__ AS)
{
  const int g = blockIdx.x, dg = blockIdx.y, c = blockIdx.z;
  const int tid = threadIdx.x;
  const int n = tid & 15, dl = tid >> 4;
  const int d0 = dg*16;
  const int d = d0 + dl;
  const int m0 = c*PP + g*16;
  __shared__ float  xdbT[16][68];   // +4 pad
  __shared__ float  dtw[16][33];    // +1 pad
  __shared__ float  dtT[16][17];
  __shared__ ushort xiT[16][16];
  {
    const int r = tid >> 4, c4 = (tid & 15)*4;
    *(float4*)&xdbT[r][c4] = *(const float4*)&xdb[(size_t)(m0 + r)*64 + c4];
    if (tid < 128){
      const int rr = tid >> 3, cc = (tid & 7)*4;
      *(float4*)&dtw[rr][cc] = *(const float4*)&dt_w[(size_t)(d0 + rr)*NDT + cc];
    }
    xiT[r][tid & 15] = ((const ushort*)xi)[(size_t)(m0 + r)*DIH + d0 + (tid & 15)];
  }
  const float a = -__expf(A_log[(size_t)d*NST + n]);
  __syncthreads();
  {
    const int j = tid >> 4, dl2 = tid & 15;
    float acc = dt_b[d0 + dl2];
    #pragma unroll
    for (int k = 0; k < 32; k++) acc += xdbT[j][k] * dtw[dl2][k];
    dtT[j][dl2] = softplusf(acc);
  }
  __syncthreads();
  float Bv[16];
  #pragma unroll
  for (int j = 0; j < 16; j++) Bv[j] = xdbT[j][32 + n];
  float s = 0.f, Ap = 1.f;
  #pragma unroll
  for (int j = 0; j < 16; j++){
    const float dtv = dtT[j][dl];
    bf16 xh; *(ushort*)&xh = xiT[j][dl];
    const float e = __expf(dtv*a);
    s = s*e + (dtv*b2f(xh))*Bv[j];
    Ap *= e;
  }
  float2 o; o.x = Ap; o.y = s;
  AS[(((size_t)(c*64+dg))*16 + g)*256 + tid] = o;
}

__launch_bounds__(256)
__global__ void scan_b(const float2* __restrict__ AS, const float* __restrict__ s0,
                       float* __restrict__ sIn)
{
  const int dg = blockIdx.x, c = blockIdx.y;
  const int tid = threadIdx.x;
  const int n = tid & 15, dl = tid >> 4;
  const int d = dg*16 + dl;
  float s = s0[((size_t)c*DIH + d)*NST + n];
  const size_t base = (((size_t)(c*64+dg))*16)*256 + tid;
  float2 f[16];
  #pragma unroll
  for (int g = 0; g < 16; g++) f[g] = AS[base + g*256];
  #pragma unroll
  for (int g = 0; g < 16; g++){
    sIn[base + g*256] = s;
    s = f[g].y + f[g].x*s;
  }
}

__launch_bounds__(256)
__global__ void scan_c(const float* __restrict__ xdb, const bf16* __restrict__ xi,
                       const bf16* __restrict__ gz,
                       const float* __restrict__ dt_w, const float* __restrict__ dt_b,
                       const float* __restrict__ A_log, const float* __restrict__ Dp,
                       const float* __restrict__ sIn,
                       bf16* __restrict__ ypre, float* __restrict__ state_out)
{
  const int g = blockIdx.x, dg = blockIdx.y, c = blockIdx.z;
  const int tid = threadIdx.x;
  const int n = tid & 15, dl = tid >> 4;
  const int d0 = dg*16;
  const int d = d0 + dl;
  const int m0 = c*PP + g*16;
  __shared__ float  xdbT[16][68];
  __shared__ float  dtw[16][33];
  __shared__ float  dtT[16][17];
  __shared__ ushort xiT[16][16];
  __shared__ ushort gzT[16][16];
  __shared__ ushort yb[16][16];
  {
    const int r = tid >> 4, c4 = (tid & 15)*4;
    *(float4*)&xdbT[r][c4] = *(const float4*)&xdb[(size_t)(m0 + r)*64 + c4];
    if (tid < 128){
      const int rr = tid >> 3, cc = (tid & 7)*4;
      *(float4*)&dtw[rr][cc] = *(const float4*)&dt_w[(size_t)(d0 + rr)*NDT + cc];
    }
    xiT[r][tid & 15] = ((const ushort*)xi)[(size_t)(m0 + r)*DIH + d0 + (tid & 15)];
    gzT[r][tid & 15] = ((const ushort*)gz)[(size_t)(m0 + r)*DIH + d0 + (tid & 15)];
  }
  const float a = -__expf(A_log[(size_t)d*NST + n]);
  const float Dv = Dp[d];
  float s = sIn[(((size_t)(c*64+dg))*16 + g)*256 + tid];
  __syncthreads();
  {
    const int j = tid >> 4, dl2 = tid & 15;
    float acc = dt_b[d0 + dl2];
    #pragma unroll
    for (int k = 0; k < 32; k++) acc += xdbT[j][k] * dtw[dl2][k];
    dtT[j][dl2] = softplusf(acc);
  }
  __syncthreads();
  float Bv[16], Cv[16];
  #pragma unroll
  for (int j = 0; j < 16; j++){ Bv[j] = xdbT[j][32 + n]; Cv[j] = xdbT[j][48 + n]; }
  #pragma unroll
  for (int j = 0; j < 16; j++){
    const float dtv = dtT[j][dl];
    bf16 xh; *(ushort*)&xh = xiT[j][dl];
    const float xiv = b2f(xh);
    const float e = __expf(dtv*a);
    s = s*e + (dtv*xiv)*Bv[j];
    float y = row_sum16(s*Cv[j]);          // valid at n==15
    if (n == 15){
      bf16 gh; *(ushort*)&gh = gzT[j][dl];
      bf16 h = f2b((y + Dv*xiv) * b2f(gh));
      yb[j][dl] = *(const ushort*)&h;
    }
  }
  __syncthreads();
  if (tid < 32){
    const int j = tid >> 1, half = tid & 1;
    ushort* dst = (ushort*)ypre + (size_t)(m0 + j)*DIH + d0 + half*8;
    *(uint4*)dst = *(const uint4*)&yb[j][half*8];
  }
  if (g == 15) state_out[((size_t)c*DIH + d)*NST + n] = s;
}

extern "C" void kernel_launch(void* const* d_in, const int* in_sizes, int n_in,
                              void* d_out, int out_size, void* d_ws, size_t ws_size,
                              hipStream_t stream) {
  const float* x       = (const float*)d_in[0];
  const float* s0      = (const float*)d_in[1];
  const float* in_w    = (const float*)d_in[2];
  const float* in_b    = (const float*)d_in[3];
  const float* conv_w  = (const float*)d_in[4];
  const float* conv_b  = (const float*)d_in[5];
  const float* param_w = (const float*)d_in[6];
  const float* param_b = (const float*)d_in[7];
  const float* dt_w    = (const float*)d_in[8];
  const float* dt_b    = (const float*)d_in[9];
  const float* out_w   = (const float*)d_in[10];
  const float* out_b   = (const float*)d_in[11];
  const float* A_log   = (const float*)d_in[12];
  const float* Dp      = (const float*)d_in[13];

  char* ws = (char*)d_ws;
  bf16*   xi    = (bf16*)ws;   ws += (size_t)MM*DIH*2;     //  8 MB (lives through scan_c)
  bf16*   gz    = (bf16*)ws;   ws += (size_t)MM*DIH*2;     //  8 MB (lives through scan_c)
  float*  xdb   = (float*)ws;  ws += (size_t)MM*64*4;      //  1 MB
  float*  cb2   = (float*)ws;  ws += 4096;                 //  4 KB
  bf16*   ypre  = (bf16*)ws;   ws += (size_t)MM*DIH*2;     //  8 MB
  bf16*   outwb = (bf16*)ws;   ws += (size_t)DMH*DIH*2;    //  1 MB
  bf16*   pwb   = (bf16*)ws;   ws += (size_t)64*DIH*2;     // 128 KB
  char*   U     = ws;          ws += (size_t)48*1024*1024; // union region, 48 MB
  // early-phase tenants of U (all dead before scan_a):
  bf16* Wfb  = (bf16*)(U);
  bf16* xbf  = (bf16*)(U + (size_t) 4*1024*1024);
  bf16* inwz = (bf16*)(U + (size_t) 8*1024*1024);
  bf16* inwT = (bf16*)(U + (size_t) 9*1024*1024);
  bf16* cwT  = (bf16*)(U + (size_t)10*1024*1024);
  // scan-phase tenants of U:
  float2* AS  = (float2*)(U);                              // 32 MB
  float*  sIn = (float*)(U + (size_t)32*1024*1024);        // 16 MB

  float* y_out  = (float*)d_out;                           // [C,P,DM] fp32
  float* st_out = y_out + (size_t)MM*DMH;                  // [C,DI,16] fp32

  // fused prep (casts, conv repack, transpose, xdb zero) + fold_bias
  prep_all<<<9536, 256, 0, stream>>>(x, in_w, out_w, param_w, conv_w,
                                     xbf, inwz, outwb, pwb, cwT, inwT, (float4*)xdb);
  fold_bias<<<DIH, 256, 0, stream>>>(conv_w, in_b, conv_b, cb2);

  // fold: Wf[k][o][m] = sum_i conv_w[o,i,k]*in_w[i,m]   (4 taps via grid.z)
  mfma_gemm<3,0,2><<<dim3(DIH/128, DMH/64, 4), 256, 0, stream>>>(
      cwT, DIH, inwT, DIH, nullptr, nullptr, Wfb, 4*DMH, DIH, DIH*DIH, DMH, 0);
  // z-half in_proj: gelu(gelu(x @ in_w_z^T + b_z)) -> gz (contiguous bf16)
  mfma_gemm<2,0,2><<<dim3(MM/128, DIH/64), 256, 0, stream>>>(
      xbf, DMH, inwz, DMH, in_b + DIH, nullptr, gz, DIH, DMH, 0, 0, 0);
  // fused conv: gelu( sum_tap x[clamp] @ Wf_tap^T + cb2 ) -> xi (contiguous bf16)
  mfma_gemm<1,1,2><<<dim3(MM/128, DIH/64), 256, 0, stream>>>(
      xbf, DMH, Wfb, 4*DMH, cb2, nullptr, xi, DIH, 4*DMH, 0, 0, 0);
  // x_db = xi @ param_w.T + param_b   (MFMA split-K=8, fp32 atomics into zeroed xdb)
  mfma_gemm<4,0,2><<<dim3(MM/128, 1, 8), 256, 0, stream>>>(
      xi, DIH, pwb, DIH, param_b, xdb, nullptr, 64, 128, 0, 0, 128);
  // chunked scan; dt GEMM fused into scan_a / scan_c
  scan_a<<<dim3(16, 64, CC), 256, 0, stream>>>(xdb, xi, dt_w, dt_b, A_log, AS);
  scan_b<<<dim3(64, CC), 256, 0, stream>>>(AS, s0, sIn);
  scan_c<<<dim3(16, 64, CC), 256, 0, stream>>>(xdb, xi, gz, dt_w, dt_b, A_log, Dp,
                                               sIn, ypre, st_out);
  // out projection
  mfma_gemm<0,0,1><<<dim3(MM/128, DMH/32), 256, 0, stream>>>(
      ypre, DIH, outwb, DIH, out_b, y_out, nullptr, DMH, DIH, 0, 0, 0);
}